// Round 18
// baseline (119.823 us; speedup 1.0000x reference)
//
#include <hip/hip_runtime.h>
#include <cstdint>
#include <cstddef>
#include <math.h>

// B=2, L=2048, E=1024, H=16, D=64
#define BB 2
#define LL 2048
#define EE 1024
#define HH 16
#define DD 64
#define MM (BB*LL)

typedef short short8 __attribute__((ext_vector_type(8)));
typedef float f32x4 __attribute__((ext_vector_type(4)));
typedef float f32x16 __attribute__((ext_vector_type(16)));

#define GPTR __attribute__((address_space(1)))
#define LPTR __attribute__((address_space(3)))

// pack 2 f32 -> 2 bf16 (RNE) in ONE VALU op
__device__ __forceinline__ unsigned pk_bf16(float lo, float hi) {
  unsigned r;
  asm("v_cvt_pk_bf16_f32 %0, %1, %2" : "=v"(r) : "v"(lo), "v"(hi));
  return r;
}
__device__ __forceinline__ unsigned short f32_bf16(float f) {
  return (unsigned short)pk_bf16(f, f);
}
// raw 2^x — defer-max bounds the arg; v_exp_f32(-inf)=0 in HW.
__device__ __forceinline__ float ex2(float x) {
  float r;
  asm("v_exp_f32 %0, %1" : "=v"(r) : "v"(x));
  return r;
}
// v_permlane32_swap_b32 vdst, vsrc — operands must be DISTINCT live values.
__device__ __forceinline__ void swap32(unsigned &a, unsigned &b) {
  asm("v_permlane32_swap_b32 %0, %1" : "+v"(a), "+v"(b));
}
__device__ __forceinline__ float xh_max(float v) {
  union { float f; unsigned u; } a, b;
  a.f = v;
  asm("v_mov_b32 %0, %1" : "=&v"(b.u) : "v"(a.u));
  asm("v_permlane32_swap_b32 %0, %1" : "+v"(a.u), "+v"(b.u));
  return fmaxf(a.f, b.f);
}
__device__ __forceinline__ float xh_sum(float v) {
  union { float f; unsigned u; } a, b;
  a.f = v;
  asm("v_mov_b32 %0, %1" : "=&v"(b.u) : "v"(a.u));
  asm("v_permlane32_swap_b32 %0, %1" : "+v"(a.u), "+v"(b.u));
  return a.f + b.f;
}
__device__ __forceinline__ f32x16 zero16() {
  f32x16 v;
  #pragma unroll
  for (int e = 0; e < 16; ++e) v[e] = 0.f;
  return v;
}

// ---------------- fp32 -> bf16 conversion (x + 4 weights fused) ----------------
__global__ void cvt_all(const float* __restrict__ x,  const float* __restrict__ wq,
                        const float* __restrict__ wk, const float* __restrict__ wv,
                        const float* __restrict__ wo,
                        unsigned short* __restrict__ xb,  unsigned short* __restrict__ wqb,
                        unsigned short* __restrict__ wkb, unsigned short* __restrict__ wvb,
                        unsigned short* __restrict__ wob)
{
  int i = (blockIdx.x * 256 + threadIdx.x) * 4;
  if (i >= MM * EE + 4 * EE * EE) return;
  const float* s; unsigned short* d; int off;
  if (i < MM * EE) { s = x; d = xb; off = i; }
  else {
    int k = i - MM * EE;
    int w = k >> 20;               // EE*EE = 1<<20
    off = k & (EE * EE - 1);
    s = (w == 0) ? wq : (w == 1) ? wk : (w == 2) ? wv : wo;
    d = (w == 0) ? wqb : (w == 1) ? wkb : (w == 2) ? wvb : wob;
  }
  float4 v = *(const float4*)(s + off);
  uint2 o;
  o.x = pk_bf16(v.x, v.y);
  o.y = pk_bf16(v.z, v.w);
  *(uint2*)(d + off) = o;
}

// ---------------- 128x128 bf16 GEMM (NT: A MxK, W NxK) — R15 proven form -------
template<int MODE>
__global__ __launch_bounds__(256, 2)
void gemm128(const unsigned short* __restrict__ A,
             const unsigned short* __restrict__ W0,
             const unsigned short* __restrict__ W1,
             const unsigned short* __restrict__ W2,
             const float* __restrict__ mask,
             const float* __restrict__ bias,
             unsigned short* __restrict__ O0,
             unsigned short* __restrict__ O1,
             unsigned short* __restrict__ O2,
             float* __restrict__ OF)
{
  constexpr int K = EE;
  const int tid = threadIdx.x;
  const int lane = tid & 63;
  const int wid = tid >> 6;
  const int g = lane >> 4, li = lane & 15;
  const int m0 = blockIdx.y * 128;
  const int n0 = blockIdx.x * 128;
  const int z = blockIdx.z;

  const unsigned short* Wp = W0;
  if (MODE == 0) Wp = (z == 0) ? W0 : ((z == 1) ? W1 : W2);

  __shared__ unsigned short As[128 * 64];
  __shared__ unsigned short Bs[128 * 64];

  f32x4 acc[4][4];
  f32x4 zero = {0.f, 0.f, 0.f, 0.f};
  #pragma unroll
  for (int i = 0; i < 4; ++i)
    #pragma unroll
    for (int j = 0; j < 4; ++j) acc[i][j] = zero;

  const int wm = (wid >> 1) * 64;
  const int wn = (wid & 1) * 64;

  for (int kt = 0; kt < K; kt += 64) {
    #pragma unroll
    for (int j = 0; j < 4; ++j) {
      int c = j * 256 + tid;
      int row = c >> 3;
      int lcol = ((c & 7) * 16) ^ ((row & 7) << 4);
      __builtin_amdgcn_global_load_lds(
        (const GPTR void*)((const char*)(A + (size_t)(m0 + row) * K + kt) + lcol),
        (LPTR void*)((char*)As + c * 16), 16, 0, 0);
      __builtin_amdgcn_global_load_lds(
        (const GPTR void*)((const char*)(Wp + (size_t)(n0 + row) * K + kt) + lcol),
        (LPTR void*)((char*)Bs + c * 16), 16, 0, 0);
    }
    __syncthreads();

    #pragma unroll
    for (int kk = 0; kk < 2; ++kk) {
      short8 a[4], b[4];
      const int colb = (kk * 32 + g * 8) * 2;
      #pragma unroll
      for (int i = 0; i < 4; ++i) {
        int ar = wm + i * 16 + li;
        a[i] = *(const short8*)((const char*)As + ar * 128 + (colb ^ ((ar & 7) << 4)));
        int br = wn + i * 16 + li;
        b[i] = *(const short8*)((const char*)Bs + br * 128 + (colb ^ ((br & 7) << 4)));
      }
      #pragma unroll
      for (int i = 0; i < 4; ++i)
        #pragma unroll
        for (int j = 0; j < 4; ++j)
          acc[i][j] = __builtin_amdgcn_mfma_f32_16x16x32_bf16(a[i], b[j], acc[i][j], 0, 0, 0);
    }
    __syncthreads();
  }

  if (MODE == 0) {
    if (z == 2) {
      // V^T kv-blocked: per head [L/32][D=64][32], each 32-kv tile = 4KB contiguous
      #pragma unroll
      for (int i = 0; i < 4; ++i) {
        int mbase = m0 + wm + i * 16 + g * 4;
        int bb2 = mbase >> 11;
        int l0  = mbase & (LL - 1);
        float mk[4];
        #pragma unroll
        for (int r = 0; r < 4; ++r) mk[r] = mask[mbase + r];
        #pragma unroll
        for (int j = 0; j < 4; ++j) {
          int n = n0 + wn + j * 16 + li;
          int h2 = n >> 6, dd2 = n & 63;
          uint2 o;
          o.x = pk_bf16(acc[i][j][0] * mk[0], acc[i][j][1] * mk[1]);
          o.y = pk_bf16(acc[i][j][2] * mk[2], acc[i][j][3] * mk[3]);
          size_t off = (size_t)(bb2 * HH + h2) * (LL * DD)
                     + (size_t)(l0 >> 5) * (DD * 32) + dd2 * 32 + (l0 & 31);
          *(uint2*)(O2 + off) = o;
        }
      }
    } else {
      unsigned short* Op = (z == 0) ? O0 : O1;
      const float sc = (z == 0) ? 0.125f * 1.44269504088896f : 1.0f;
      #pragma unroll
      for (int i = 0; i < 4; ++i) {
        #pragma unroll
        for (int r = 0; r < 4; ++r) {
          int m = m0 + wm + i * 16 + g * 4 + r;
          float mk = mask[m] * sc;
          int bb = m >> 11;
          int l  = m & (LL - 1);
          #pragma unroll
          for (int j = 0; j < 4; ++j) {
            int n = n0 + wn + j * 16 + li;
            int h = n >> 6, d = n & 63;
            size_t off = (((size_t)(bb * HH + h)) * LL + l) * DD + d;
            Op[off] = f32_bf16(acc[i][j][r] * mk);
          }
        }
      }
    }
  } else {
    #pragma unroll
    for (int i = 0; i < 4; ++i) {
      #pragma unroll
      for (int j = 0; j < 4; ++j) {
        int n = n0 + wn + j * 16 + li;
        float bv = bias[n];
        #pragma unroll
        for (int r = 0; r < 4; ++r) {
          int m = m0 + wm + i * 16 + g * 4 + r;
          OF[(size_t)m * EE + n] = acc[i][j][r] + bv;
        }
      }
    }
  }
}

// ---------------- causal flash attention: 4 waves/SIMD via 2048 lean blocks ----
// One q-tile per block (2048 blocks = 8 blocks/CU = 16 waves/CU = 4 waves/SIMD).
// 2 waves kv-parity; NO register ping-pong (state fits the 128-VGPR/4-wave cap);
// exposed per-body loads covered by TLP. Heavy q-tiles first within each XCD.
// Softmax: local-max defer check, per-lane partial lsum (attn11's proven math).
__global__ __launch_bounds__(128, 4)
void attn13(const unsigned short* __restrict__ Q,
            const unsigned short* __restrict__ K,
            const unsigned short* __restrict__ VT,
            unsigned short* __restrict__ Y)
{
  const int tid = threadIdx.x, lane = tid & 63, w = tid >> 6;
  const int l31 = lane & 31, hi = lane >> 5;

  const int id = blockIdx.x;                // 2048 blocks
  const int lo = id & 7;                    // XCD
  const int r_ = id >> 3;                   // 0..255 per XCD
  const int bh = (r_ & 3) * 8 + lo;         // 4 heads per XCD
  const int qt = 63 - (r_ >> 2);            // heavy q-tiles first
  const int b = bh >> 4, h = bh & (HH - 1);
  const size_t kbase = (size_t)bh * LL * DD;

  const unsigned short* Kg  = K + kbase;
  const unsigned short* VTg = VT + kbase;   // kv-blocked [L/32][64][32]

  const int qrow = qt * 32 + l31;

  short8 qf[4];
  {
    const unsigned short* Qr = Q + kbase + (size_t)qrow * DD + hi * 8;
    #pragma unroll
    for (int kc = 0; kc < 4; ++kc) qf[kc] = *(const short8*)(Qr + kc * 16);
  }

  const f32x16 kZero = zero16();
  f32x16 o0 = zero16(), o1 = zero16();
  float mq = -INFINITY;
  float ls4[4] = {0.f, 0.f, 0.f, 0.f};

  short8 kA[4], vA[4];

  for (int t = w; t <= qt; t += 2) {
    // load tile t (no ping-pong: TLP at 4 waves/SIMD hides the L2 latency)
    {
      const int kv0 = t << 5;
      const unsigned short* Kp = Kg + ((size_t)(kv0 + l31) << 6) + hi * 8;
      #pragma unroll
      for (int kc = 0; kc < 4; ++kc) kA[kc] = *(const short8*)(Kp + kc * 16);
      const unsigned short* Vp = VTg + (size_t)(kv0 >> 5) * (DD * 32) + l31 * 32 + hi * 8;
      vA[0] = *(const short8*)(Vp);
      vA[1] = *(const short8*)(Vp + 16);
      vA[2] = *(const short8*)(Vp + 32 * 32);
      vA[3] = *(const short8*)(Vp + 32 * 32 + 16);
    }

    // S^T = K·Q^T: two independent 2-deep MFMA chains + vector add
    f32x16 s;
    {
      f32x16 s0 = __builtin_amdgcn_mfma_f32_32x32x16_bf16(kA[0], qf[0], kZero, 0, 0, 0);
      f32x16 s1 = __builtin_amdgcn_mfma_f32_32x32x16_bf16(kA[1], qf[1], kZero, 0, 0, 0);
      s0 = __builtin_amdgcn_mfma_f32_32x32x16_bf16(kA[2], qf[2], s0, 0, 0, 0);
      s1 = __builtin_amdgcn_mfma_f32_32x32x16_bf16(kA[3], qf[3], s1, 0, 0, 0);
      #pragma unroll
      for (int e = 0; e < 16; ++e) s0[e] += s1[e];
      s = s0;
    }

    // causal mask on the diagonal tile
    if (t == qt) {
      #pragma unroll
      for (int i = 0; i < 16; ++i) {
        int kvr = (i & 3) + 8 * (i >> 2) + 4 * hi;
        if (kvr > l31) s[i] = -INFINITY;
      }
    }

    // online softmax: local-max defer check, per-lane partial sums
    float r0 = fmaxf(fmaxf(fmaxf(s[0], s[8]),  fmaxf(s[1], s[9])),  fmaxf(s[2], s[10]));
    float r1 = fmaxf(fmaxf(fmaxf(s[3], s[11]), fmaxf(s[4], s[12])), fmaxf(s[5], s[13]));
    float r2 = fmaxf(fmaxf(s[6], s[14]), fmaxf(s[7], s[15]));
    float mv = fmaxf(fmaxf(r0, r1), r2);     // LOCAL (half-row) max

    if (!__all(mv <= mq + 8.0f)) {           // __all spans all 64 lanes
      float mnew = fmaxf(mq, xh_max(mv));    // row max — RARE path only
      float al = ex2(mq - mnew);             // mq=-inf -> 0, correct
      mq = mnew;
      #pragma unroll
      for (int e = 0; e < 16; ++e) { o0[e] *= al; o1[e] *= al; }
      #pragma unroll
      for (int e = 0; e < 4; ++e) ls4[e] *= al;
    }

    #pragma unroll
    for (int e = 0; e < 16; ++e) s[e] = ex2(s[e] - mq);
    ls4[0] += (s[0] + s[8])  + (s[4] + s[12]);
    ls4[1] += (s[1] + s[9])  + (s[5] + s[13]);
    ls4[2] += (s[2] + s[10]) + (s[6] + s[14]);
    ls4[3] += (s[3] + s[11]) + (s[7] + s[15]);

    // P fragments: cvt_pk + permlane32_swap (T12)
    auto mkfrag = [&](int base) -> short8 {
      unsigned a0 = pk_bf16(s[base + 0], s[base + 1]);
      unsigned a1 = pk_bf16(s[base + 2], s[base + 3]);
      unsigned b0 = pk_bf16(s[base + 4], s[base + 5]);
      unsigned b1 = pk_bf16(s[base + 6], s[base + 7]);
      swap32(a0, b0);
      swap32(a1, b1);
      union { unsigned u[4]; short8 s8; } f;
      f.u[0] = a0; f.u[1] = a1; f.u[2] = b0; f.u[3] = b1;
      return f.s8;
    };
    short8 pf0 = mkfrag(0), pf1 = mkfrag(8);

    o0 = __builtin_amdgcn_mfma_f32_32x32x16_bf16(vA[0], pf0, o0, 0, 0, 0);
    o1 = __builtin_amdgcn_mfma_f32_32x32x16_bf16(vA[2], pf0, o1, 0, 0, 0);
    o0 = __builtin_amdgcn_mfma_f32_32x32x16_bf16(vA[1], pf1, o0, 0, 0, 0);
    o1 = __builtin_amdgcn_mfma_f32_32x32x16_bf16(vA[3], pf1, o1, 0, 0, 0);
  }

  // collapse partials to one half-row value per lane
  float lq = (ls4[0] + ls4[1]) + (ls4[2] + ls4[3]);

  // ---- merge the two waves' partials via LDS (single barrier) ----
  __shared__ float mg[64][34];
  if (w == 1) {
    mg[lane][0] = mq; mg[lane][1] = lq;
    #pragma unroll
    for (int e = 0; e < 16; ++e) {
      mg[lane][2 + e] = o0[e]; mg[lane][18 + e] = o1[e];
    }
  }
  __syncthreads();
  if (w == 0) {
    float m1 = mg[lane][0], l1 = mg[lane][1];
    float M = fmaxf(mq, m1);
    float a0 = ex2(fmaxf(mq - M, -200.0f));   // -inf-(-inf) NaN guard
    float a1 = ex2(fmaxf(m1 - M, -200.0f));
    float LtH = lq * a0 + l1 * a1;            // half-row total
    float Lt = xh_sum(LtH);                   // row total (single permlane)
    float inv = 1.0f / Lt;
    unsigned short* Yr = Y + ((size_t)b * LL + qrow) * EE + h * DD;
    #pragma unroll
    for (int rg = 0; rg < 4; ++rg) {
      uint2 u0, u1;
      int i = rg * 4;
      u0.x = pk_bf16((o0[i]     * a0 + mg[lane][2 + i]  * a1) * inv,
                     (o0[i + 1] * a0 + mg[lane][3 + i]  * a1) * inv);
      u0.y = pk_bf16((o0[i + 2] * a0 + mg[lane][4 + i]  * a1) * inv,
                     (o0[i + 3] * a0 + mg[lane][5 + i]  * a1) * inv);
      u1.x = pk_bf16((o1[i]     * a0 + mg[lane][18 + i] * a1) * inv,
                     (o1[i + 1] * a0 + mg[lane][19 + i] * a1) * inv);
      u1.y = pk_bf16((o1[i + 2] * a0 + mg[lane][20 + i] * a1) * inv,
                     (o1[i + 3] * a0 + mg[lane][21 + i] * a1) * inv);
      *(uint2*)(Yr + rg * 8 + hi * 4) = u0;
      *(uint2*)(Yr + 32 + rg * 8 + hi * 4) = u1;
    }
  }
}

// ---------------- launch ----------------
extern "C" void kernel_launch(void* const* d_in, const int* in_sizes, int n_in,
                              void* d_out, int out_size, void* d_ws, size_t ws_size,
                              hipStream_t stream) {
  const float* x    = (const float*)d_in[0];
  const float* mask = (const float*)d_in[1];
  const float* Wq   = (const float*)d_in[2];
  const float* Wk   = (const float*)d_in[3];
  const float* Wv   = (const float*)d_in[4];
  const float* Wo   = (const float*)d_in[5];
  const float* bo   = (const float*)d_in[6];
  float* out = (float*)d_out;

  char* ws = (char*)d_ws;
  unsigned short* xb  = (unsigned short*)(ws);
  unsigned short* wqb = (unsigned short*)(ws + ((size_t)8  << 20));
  unsigned short* wkb = (unsigned short*)(ws + ((size_t)10 << 20));
  unsigned short* wvb = (unsigned short*)(ws + ((size_t)12 << 20));
  unsigned short* wob = (unsigned short*)(ws + ((size_t)14 << 20));
  unsigned short* Qb  = (unsigned short*)(ws + ((size_t)16 << 20));
  unsigned short* Kb  = (unsigned short*)(ws + ((size_t)24 << 20));
  unsigned short* VTb = (unsigned short*)(ws + ((size_t)32 << 20));
  unsigned short* Yb  = (unsigned short*)(ws + ((size_t)40 << 20));

  cvt_all<<<8192, 256, 0, stream>>>(x, Wq, Wk, Wv, Wo, xb, wqb, wkb, wvb, wob);

  gemm128<0><<<dim3(EE / 128, MM / 128, 3), 256, 0, stream>>>(
      xb, wqb, wkb, wvb, mask, nullptr, Qb, Kb, VTb, nullptr);

  attn13<<<dim3(2048), 128, 0, stream>>>(Qb, Kb, VTb, Yb);

  gemm128<1><<<dim3(EE / 128, MM / 128, 1), 256, 0, stream>>>(
      Yb, wob, nullptr, nullptr, nullptr, bo, nullptr, nullptr, nullptr, out);
}

// Round 19
// 107.332 us; speedup vs baseline: 1.1164x; 1.1164x over previous
//
#include <hip/hip_runtime.h>
#include <cstdint>
#include <cstddef>
#include <math.h>

// B=2, L=2048, E=1024, H=16, D=64
#define BB 2
#define LL 2048
#define EE 1024
#define HH 16
#define DD 64
#define MM (BB*LL)

typedef short short8 __attribute__((ext_vector_type(8)));
typedef float f32x4 __attribute__((ext_vector_type(4)));
typedef float f32x16 __attribute__((ext_vector_type(16)));

#define GPTR __attribute__((address_space(1)))
#define LPTR __attribute__((address_space(3)))

// pack 2 f32 -> 2 bf16 (RNE) in ONE VALU op
__device__ __forceinline__ unsigned pk_bf16(float lo, float hi) {
  unsigned r;
  asm("v_cvt_pk_bf16_f32 %0, %1, %2" : "=v"(r) : "v"(lo), "v"(hi));
  return r;
}
__device__ __forceinline__ unsigned short f32_bf16(float f) {
  return (unsigned short)pk_bf16(f, f);
}
// raw 2^x — defer-max bounds the arg; v_exp_f32(-inf)=0 in HW.
__device__ __forceinline__ float ex2(float x) {
  float r;
  asm("v_exp_f32 %0, %1" : "=v"(r) : "v"(x));
  return r;
}
// v_permlane32_swap_b32 vdst, vsrc — operands must be DISTINCT live values.
__device__ __forceinline__ void swap32(unsigned &a, unsigned &b) {
  asm("v_permlane32_swap_b32 %0, %1" : "+v"(a), "+v"(b));
}
__device__ __forceinline__ float xh_max(float v) {
  union { float f; unsigned u; } a, b;
  a.f = v;
  asm("v_mov_b32 %0, %1" : "=&v"(b.u) : "v"(a.u));
  asm("v_permlane32_swap_b32 %0, %1" : "+v"(a.u), "+v"(b.u));
  return fmaxf(a.f, b.f);
}
__device__ __forceinline__ float xh_sum(float v) {
  union { float f; unsigned u; } a, b;
  a.f = v;
  asm("v_mov_b32 %0, %1" : "=&v"(b.u) : "v"(a.u));
  asm("v_permlane32_swap_b32 %0, %1" : "+v"(a.u), "+v"(b.u));
  return a.f + b.f;
}
__device__ __forceinline__ f32x16 zero16() {
  f32x16 v;
  #pragma unroll
  for (int e = 0; e < 16; ++e) v[e] = 0.f;
  return v;
}

// ---------------- fp32 -> bf16 conversion (x + 4 weights fused) ----------------
__global__ void cvt_all(const float* __restrict__ x,  const float* __restrict__ wq,
                        const float* __restrict__ wk, const float* __restrict__ wv,
                        const float* __restrict__ wo,
                        unsigned short* __restrict__ xb,  unsigned short* __restrict__ wqb,
                        unsigned short* __restrict__ wkb, unsigned short* __restrict__ wvb,
                        unsigned short* __restrict__ wob)
{
  int i = (blockIdx.x * 256 + threadIdx.x) * 4;
  if (i >= MM * EE + 4 * EE * EE) return;
  const float* s; unsigned short* d; int off;
  if (i < MM * EE) { s = x; d = xb; off = i; }
  else {
    int k = i - MM * EE;
    int w = k >> 20;               // EE*EE = 1<<20
    off = k & (EE * EE - 1);
    s = (w == 0) ? wq : (w == 1) ? wk : (w == 2) ? wv : wo;
    d = (w == 0) ? wqb : (w == 1) ? wkb : (w == 2) ? wvb : wob;
  }
  float4 v = *(const float4*)(s + off);
  uint2 o;
  o.x = pk_bf16(v.x, v.y);
  o.y = pk_bf16(v.z, v.w);
  *(uint2*)(d + off) = o;
}

// ---------------- 128x128 bf16 GEMM (NT: A MxK, W NxK) ----------------
// __launch_bounds__(256,3): 3 blocks/CU (12 waves/CU) — matches the m97
// reference config (874-912 TF ran at ~3 blocks/CU); (256,2) under-subscribed.
template<int MODE>
__global__ __launch_bounds__(256, 3)
void gemm128(const unsigned short* __restrict__ A,
             const unsigned short* __restrict__ W0,
             const unsigned short* __restrict__ W1,
             const unsigned short* __restrict__ W2,
             const float* __restrict__ mask,
             const float* __restrict__ bias,
             unsigned short* __restrict__ O0,
             unsigned short* __restrict__ O1,
             unsigned short* __restrict__ O2,
             float* __restrict__ OF)
{
  constexpr int K = EE;
  const int tid = threadIdx.x;
  const int lane = tid & 63;
  const int wid = tid >> 6;
  const int g = lane >> 4, li = lane & 15;
  const int m0 = blockIdx.y * 128;
  const int n0 = blockIdx.x * 128;
  const int z = blockIdx.z;

  const unsigned short* Wp = W0;
  if (MODE == 0) Wp = (z == 0) ? W0 : ((z == 1) ? W1 : W2);

  __shared__ unsigned short As[128 * 64];
  __shared__ unsigned short Bs[128 * 64];

  f32x4 acc[4][4];
  f32x4 zero = {0.f, 0.f, 0.f, 0.f};
  #pragma unroll
  for (int i = 0; i < 4; ++i)
    #pragma unroll
    for (int j = 0; j < 4; ++j) acc[i][j] = zero;

  const int wm = (wid >> 1) * 64;
  const int wn = (wid & 1) * 64;

  for (int kt = 0; kt < K; kt += 64) {
    #pragma unroll
    for (int j = 0; j < 4; ++j) {
      int c = j * 256 + tid;
      int row = c >> 3;
      int lcol = ((c & 7) * 16) ^ ((row & 7) << 4);
      __builtin_amdgcn_global_load_lds(
        (const GPTR void*)((const char*)(A + (size_t)(m0 + row) * K + kt) + lcol),
        (LPTR void*)((char*)As + c * 16), 16, 0, 0);
      __builtin_amdgcn_global_load_lds(
        (const GPTR void*)((const char*)(Wp + (size_t)(n0 + row) * K + kt) + lcol),
        (LPTR void*)((char*)Bs + c * 16), 16, 0, 0);
    }
    __syncthreads();

    #pragma unroll
    for (int kk = 0; kk < 2; ++kk) {
      short8 a[4], b[4];
      const int colb = (kk * 32 + g * 8) * 2;
      #pragma unroll
      for (int i = 0; i < 4; ++i) {
        int ar = wm + i * 16 + li;
        a[i] = *(const short8*)((const char*)As + ar * 128 + (colb ^ ((ar & 7) << 4)));
        int br = wn + i * 16 + li;
        b[i] = *(const short8*)((const char*)Bs + br * 128 + (colb ^ ((br & 7) << 4)));
      }
      #pragma unroll
      for (int i = 0; i < 4; ++i)
        #pragma unroll
        for (int j = 0; j < 4; ++j)
          acc[i][j] = __builtin_amdgcn_mfma_f32_16x16x32_bf16(a[i], b[j], acc[i][j], 0, 0, 0);
    }
    __syncthreads();
  }

  if (MODE == 0) {
    if (z == 2) {
      // V^T kv-blocked: per head [L/32][D=64][32], each 32-kv tile = 4KB contiguous
      #pragma unroll
      for (int i = 0; i < 4; ++i) {
        int mbase = m0 + wm + i * 16 + g * 4;
        int bb2 = mbase >> 11;
        int l0  = mbase & (LL - 1);
        float mk[4];
        #pragma unroll
        for (int r = 0; r < 4; ++r) mk[r] = mask[mbase + r];
        #pragma unroll
        for (int j = 0; j < 4; ++j) {
          int n = n0 + wn + j * 16 + li;
          int h2 = n >> 6, dd2 = n & 63;
          uint2 o;
          o.x = pk_bf16(acc[i][j][0] * mk[0], acc[i][j][1] * mk[1]);
          o.y = pk_bf16(acc[i][j][2] * mk[2], acc[i][j][3] * mk[3]);
          size_t off = (size_t)(bb2 * HH + h2) * (LL * DD)
                     + (size_t)(l0 >> 5) * (DD * 32) + dd2 * 32 + (l0 & 31);
          *(uint2*)(O2 + off) = o;
        }
      }
    } else {
      unsigned short* Op = (z == 0) ? O0 : O1;
      const float sc = (z == 0) ? 0.125f * 1.44269504088896f : 1.0f;
      #pragma unroll
      for (int i = 0; i < 4; ++i) {
        #pragma unroll
        for (int r = 0; r < 4; ++r) {
          int m = m0 + wm + i * 16 + g * 4 + r;
          float mk = mask[m] * sc;
          int bb = m >> 11;
          int l  = m & (LL - 1);
          #pragma unroll
          for (int j = 0; j < 4; ++j) {
            int n = n0 + wn + j * 16 + li;
            int h = n >> 6, d = n & 63;
            size_t off = (((size_t)(bb * HH + h)) * LL + l) * DD + d;
            Op[off] = f32_bf16(acc[i][j][r] * mk);
          }
        }
      }
    }
  } else {
    #pragma unroll
    for (int i = 0; i < 4; ++i) {
      #pragma unroll
      for (int j = 0; j < 4; ++j) {
        int n = n0 + wn + j * 16 + li;
        float bv = bias[n];
        #pragma unroll
        for (int r = 0; r < 4; ++r) {
          int m = m0 + wm + i * 16 + g * 4 + r;
          OF[(size_t)m * EE + n] = acc[i][j][r] + bv;
        }
      }
    }
  }
}

// ---------------- causal flash attention: attn11 (proven best, 46.6 µs) --------
// Block p handles q-tiles qth=63-p AND qtl=p (65 processes, balanced). 2 waves
// kv-parity split; local-max defer check (cross-lane only on rare rescale path);
// per-lane partial lsum (cross-half sum deferred to final merge).
__global__ __launch_bounds__(128, 2)
void attn11(const unsigned short* __restrict__ Q,
            const unsigned short* __restrict__ K,
            const unsigned short* __restrict__ VT,
            unsigned short* __restrict__ Y)
{
  const int tid = threadIdx.x, lane = tid & 63, w = tid >> 6;
  const int l31 = lane & 31, hi = lane >> 5;

  const int id = blockIdx.x;
  const int lo = id & 7;                    // XCD
  const int r_ = id >> 3;
  const int bh = (r_ & 3) * 8 + lo;         // 4 heads per XCD
  const int p  = r_ >> 2;                   // pair index 0..31
  const int qth = 63 - p;                   // heavy q-tile (32..63)
  const int qtl = p;                        // light q-tile (0..31)
  const int b = bh >> 4, h = bh & (HH - 1);
  const size_t kbase = (size_t)bh * LL * DD;

  const unsigned short* Kg  = K + kbase;
  const unsigned short* VTg = VT + kbase;   // kv-blocked [L/32][64][32]

  const int qrh = qth * 32 + l31;
  const int qrl = qtl * 32 + l31;

  short8 qfh[4], qfl[4];
  {
    const unsigned short* Qr = Q + kbase + (size_t)qrh * DD + hi * 8;
    #pragma unroll
    for (int kc = 0; kc < 4; ++kc) qfh[kc] = *(const short8*)(Qr + kc * 16);
    const unsigned short* Qs = Q + kbase + (size_t)qrl * DD + hi * 8;
    #pragma unroll
    for (int kc = 0; kc < 4; ++kc) qfl[kc] = *(const short8*)(Qs + kc * 16);
  }

  const f32x16 kZero = zero16();            // loop-invariant C-seed for QK^T
  f32x16 oh0 = zero16(), oh1 = zero16(), ol0 = zero16(), ol1 = zero16();
  float mh = -INFINITY, ml = -INFINITY;
  float lsh4[4] = {0.f, 0.f, 0.f, 0.f};     // per-lane HALF-ROW partial sums
  float lsl4[4] = {0.f, 0.f, 0.f, 0.f};

  short8 kA[4], vA[4], kB[4], vB[4];

  auto loadtile = [&](short8 (&kk)[4], short8 (&vv)[4], int t2) {
    const int kv0 = t2 << 5;
    const unsigned short* Kp = Kg + ((size_t)(kv0 + l31) << 6) + hi * 8;
    #pragma unroll
    for (int kc = 0; kc < 4; ++kc) kk[kc] = *(const short8*)(Kp + kc * 16);
    const unsigned short* Vp = VTg + (size_t)(kv0 >> 5) * (DD * 32) + l31 * 32 + hi * 8;
    vv[0] = *(const short8*)(Vp);
    vv[1] = *(const short8*)(Vp + 16);
    vv[2] = *(const short8*)(Vp + 32 * 32);
    vv[3] = *(const short8*)(Vp + 32 * 32 + 16);
  };

  loadtile(kA, vA, w);

  // QK^T: two independent 2-deep MFMA chains + vector add
  auto qk = [&](const short8 (&ck)[4], const short8 (&qf)[4]) -> f32x16 {
    f32x16 s0 = __builtin_amdgcn_mfma_f32_32x32x16_bf16(ck[0], qf[0], kZero, 0, 0, 0);
    f32x16 s1 = __builtin_amdgcn_mfma_f32_32x32x16_bf16(ck[1], qf[1], kZero, 0, 0, 0);
    s0 = __builtin_amdgcn_mfma_f32_32x32x16_bf16(ck[2], qf[2], s0, 0, 0, 0);
    s1 = __builtin_amdgcn_mfma_f32_32x32x16_bf16(ck[3], qf[3], s1, 0, 0, 0);
    #pragma unroll
    for (int e = 0; e < 16; ++e) s0[e] += s1[e];
    return s0;
  };

  auto diagmask = [&](f32x16 &s) {
    #pragma unroll
    for (int i = 0; i < 16; ++i) {
      int kvr = (i & 3) + 8 * (i >> 2) + 4 * hi;
      if (kvr > l31) s[i] = -INFINITY;
    }
  };

  // online softmax: local-max defer check, per-lane partial lsum accumulators.
  auto process = [&](f32x16 &s, const short8 (&cv)[4],
                     float &mq, float (&ls4)[4], f32x16 &o0, f32x16 &o1) {
    float r0 = fmaxf(fmaxf(fmaxf(s[0], s[8]),  fmaxf(s[1], s[9])),  fmaxf(s[2], s[10]));
    float r1 = fmaxf(fmaxf(fmaxf(s[3], s[11]), fmaxf(s[4], s[12])), fmaxf(s[5], s[13]));
    float r2 = fmaxf(fmaxf(s[6], s[14]), fmaxf(s[7], s[15]));
    float mv = fmaxf(fmaxf(r0, r1), r2);     // LOCAL (half-row) max

    if (!__all(mv <= mq + 8.0f)) {           // __all spans all 64 lanes
      float mnew = fmaxf(mq, xh_max(mv));    // row max — RARE path only
      float al = ex2(mq - mnew);             // mq=-inf -> 0, correct
      mq = mnew;
      #pragma unroll
      for (int e = 0; e < 16; ++e) { o0[e] *= al; o1[e] *= al; }
      #pragma unroll
      for (int e = 0; e < 4; ++e) ls4[e] *= al;
    }

    #pragma unroll
    for (int e = 0; e < 16; ++e) s[e] = ex2(s[e] - mq);
    ls4[0] += (s[0] + s[8])  + (s[4] + s[12]);
    ls4[1] += (s[1] + s[9])  + (s[5] + s[13]);
    ls4[2] += (s[2] + s[10]) + (s[6] + s[14]);
    ls4[3] += (s[3] + s[11]) + (s[7] + s[15]);

    auto mkfrag = [&](int base) -> short8 {
      unsigned a0 = pk_bf16(s[base + 0], s[base + 1]);
      unsigned a1 = pk_bf16(s[base + 2], s[base + 3]);
      unsigned b0 = pk_bf16(s[base + 4], s[base + 5]);
      unsigned b1 = pk_bf16(s[base + 6], s[base + 7]);
      swap32(a0, b0);
      swap32(a1, b1);
      union { unsigned u[4]; short8 s8; } f;
      f.u[0] = a0; f.u[1] = a1; f.u[2] = b0; f.u[3] = b1;
      return f.s8;
    };
    short8 pf0 = mkfrag(0), pf1 = mkfrag(8);

    o0 = __builtin_amdgcn_mfma_f32_32x32x16_bf16(cv[0], pf0, o0, 0, 0, 0);
    o1 = __builtin_amdgcn_mfma_f32_32x32x16_bf16(cv[2], pf0, o1, 0, 0, 0);
    o0 = __builtin_amdgcn_mfma_f32_32x32x16_bf16(cv[1], pf1, o0, 0, 0, 0);
    o1 = __builtin_amdgcn_mfma_f32_32x32x16_bf16(cv[3], pf1, o1, 0, 0, 0);
  };

  auto body = [&](short8 (&ck)[4], short8 (&cv)[4],
                  short8 (&nk)[4], short8 (&nv)[4], int t) {
    if (t + 2 <= qth) loadtile(nk, nv, t + 2);

    if (t <= qtl) {
      f32x16 sh = qk(ck, qfh);
      f32x16 sl = qk(ck, qfl);
      if (t == qtl) diagmask(sl);      // qth > qtl always
      process(sh, cv, mh, lsh4, oh0, oh1);
      process(sl, cv, ml, lsl4, ol0, ol1);
    } else {
      f32x16 sh = qk(ck, qfh);
      if (t == qth) diagmask(sh);
      process(sh, cv, mh, lsh4, oh0, oh1);
    }
  };

  for (int t = w; t <= qth; t += 4) {
    body(kA, vA, kB, vB, t);
    if (t + 2 <= qth) body(kB, vB, kA, vA, t + 2);
  }

  // collapse partials to one half-row value per lane (cross-half at merge)
  float lsh = (lsh4[0] + lsh4[1]) + (lsh4[2] + lsh4[3]);
  float lsl = (lsl4[0] + lsl4[1]) + (lsl4[2] + lsl4[3]);

  // ---- merge the two waves' partials via LDS (single barrier), both q-tiles ----
  __shared__ float mg[2][64][34];
  if (w == 1) {
    mg[0][lane][0] = mh; mg[0][lane][1] = lsh;
    mg[1][lane][0] = ml; mg[1][lane][1] = lsl;
    #pragma unroll
    for (int e = 0; e < 16; ++e) {
      mg[0][lane][2 + e] = oh0[e]; mg[0][lane][18 + e] = oh1[e];
      mg[1][lane][2 + e] = ol0[e]; mg[1][lane][18 + e] = ol1[e];
    }
  }
  __syncthreads();
  if (w == 0) {
    #pragma unroll
    for (int q = 0; q < 2; ++q) {
      float mw = (q == 0) ? mh : ml;
      float lw = (q == 0) ? lsh : lsl;
      const f32x16& o0 = (q == 0) ? oh0 : ol0;
      const f32x16& o1 = (q == 0) ? oh1 : ol1;
      int qrow = (q == 0) ? qrh : qrl;
      float m1 = mg[q][lane][0], l1 = mg[q][lane][1];
      float M = fmaxf(mw, m1);
      float a0 = ex2(fmaxf(mw - M, -200.0f));   // -inf-(-inf) NaN guard
      float a1 = ex2(fmaxf(m1 - M, -200.0f));
      float LtH = lw * a0 + l1 * a1;            // half-row total
      float Lt = xh_sum(LtH);                   // row total (single permlane)
      float inv = 1.0f / Lt;
      unsigned short* Yr = Y + ((size_t)b * LL + qrow) * EE + h * DD;
      #pragma unroll
      for (int rg = 0; rg < 4; ++rg) {
        uint2 u0, u1;
        int i = rg * 4;
        u0.x = pk_bf16((o0[i]     * a0 + mg[q][lane][2 + i]     * a1) * inv,
                       (o0[i + 1] * a0 + mg[q][lane][3 + i]     * a1) * inv);
        u0.y = pk_bf16((o0[i + 2] * a0 + mg[q][lane][4 + i]     * a1) * inv,
                       (o0[i + 3] * a0 + mg[q][lane][5 + i]     * a1) * inv);
        u1.x = pk_bf16((o1[i]     * a0 + mg[q][lane][18 + i]    * a1) * inv,
                       (o1[i + 1] * a0 + mg[q][lane][19 + i]    * a1) * inv);
        u1.y = pk_bf16((o1[i + 2] * a0 + mg[q][lane][20 + i]    * a1) * inv,
                       (o1[i + 3] * a0 + mg[q][lane][21 + i]    * a1) * inv);
        *(uint2*)(Yr + rg * 8 + hi * 4) = u0;
        *(uint2*)(Yr + 32 + rg * 8 + hi * 4) = u1;
      }
    }
  }
}

// ---------------- launch ----------------
extern "C" void kernel_launch(void* const* d_in, const int* in_sizes, int n_in,
                              void* d_out, int out_size, void* d_ws, size_t ws_size,
                              hipStream_t stream) {
  const float* x    = (const float*)d_in[0];
  const float* mask = (const float*)d_in[1];
  const float* Wq   = (const float*)d_in[2];
  const float* Wk   = (const float*)d_in[3];
  const float* Wv   = (const float*)d_in[4];
  const float* Wo   = (const float*)d_in[5];
  const float* bo   = (const float*)d_in[6];
  float* out = (float*)d_out;

  char* ws = (char*)d_ws;
  unsigned short* xb  = (unsigned short*)(ws);
  unsigned short* wqb = (unsigned short*)(ws + ((size_t)8  << 20));
  unsigned short* wkb = (unsigned short*)(ws + ((size_t)10 << 20));
  unsigned short* wvb = (unsigned short*)(ws + ((size_t)12 << 20));
  unsigned short* wob = (unsigned short*)(ws + ((size_t)14 << 20));
  unsigned short* Qb  = (unsigned short*)(ws + ((size_t)16 << 20));
  unsigned short* Kb  = (unsigned short*)(ws + ((size_t)24 << 20));
  unsigned short* VTb = (unsigned short*)(ws + ((size_t)32 << 20));
  unsigned short* Yb  = (unsigned short*)(ws + ((size_t)40 << 20));

  cvt_all<<<8192, 256, 0, stream>>>(x, Wq, Wk, Wv, Wo, xb, wqb, wkb, wvb, wob);

  gemm128<0><<<dim3(EE / 128, MM / 128, 3), 256, 0, stream>>>(
      xb, wqb, wkb, wvb, mask, nullptr, Qb, Kb, VTb, nullptr);

  attn11<<<dim3(1024), 128, 0, stream>>>(Qb, Kb, VTb, Yb);

  gemm128<1><<<dim3(EE / 128, MM / 128, 1), 256, 0, stream>>>(
      Yb, wob, nullptr, nullptr, nullptr, bo, nullptr, nullptr, nullptr, out);
}